// Round 1
// baseline (145.138 us; speedup 1.0000x reference)
//
#include <hip/hip_runtime.h>
#include <hip/hip_bf16.h>

typedef __attribute__((ext_vector_type(8))) short short8;
typedef __attribute__((ext_vector_type(4))) float float4v;
typedef __attribute__((ext_vector_type(4))) int int4v;

#define S_A 0.04419417382415922f   // 1/(16*sqrt(2)) : a2, and a1*s2
#define S_B 0.025515518153991442f  // 1/(16*sqrt(6)) : a2/sqrt(3), and a1/sqrt(6)
#define S_C 0.0625f                // 1/16 : a1

static __device__ __forceinline__ unsigned short f2bfu(float f) {
    __hip_bfloat16 h = __float2bfloat16(f);
    return __builtin_bit_cast(unsigned short, h);
}

static __device__ __forceinline__ unsigned pack_bf2(float a, float b) {
    return ((unsigned)f2bfu(b) << 16) | (unsigned)f2bfu(a);
}

// One wave = one z-tile of 16 rows. Block = 4 waves = 64 rows.
// GEMM per m-slot: out_m[z(16), w(16)] += A_m[z,k] * W_m[k,w], K = 256 (uv), 8 chunks of 32.
// A-frag (16x16x32 bf16): lane l holds A[row=l&15][k = chunk*32 + (l>>4)*8 + j], j=0..7
// B-frag:                 lane l holds W[k = chunk*32 + (l>>4)*8 + j][w=l&15]
// C/D:                    lane l, reg r -> D[row=(l>>4)*4+r][col=l&15]   (guide m89/m91)
__global__ __launch_bounds__(256, 2)
void tsq_kernel(const float* __restrict__ x,
                const float* __restrict__ wA,   // w0  (0e x 0e -> 0e)
                const float* __restrict__ wB,   // w2  (1o x 1o -> 0e)
                const float* __restrict__ wC,   // w1  (0e x 1o -> 1o)
                const float* __restrict__ wD,   // w3  (1o x 1o -> 1e)
                const float* __restrict__ wE,   // w4  (1o x 1o -> 2e)
                float* __restrict__ out,
                int nrows)
{
    // W in B-frag layout: [path][chunk][lane][j] bf16 = 40 KB
    __shared__ __attribute__((aligned(16))) unsigned short wlds[5 * 8 * 64 * 8];
    // x tile: 64 rows x 64 floats, padded stride 68 (68%32=4 -> rotate banks)
    __shared__ __attribute__((aligned(16))) float xlds[64 * 68];

    const int tid = threadIdx.x;

    // ---- Phase 0: W -> bf16 -> LDS in fragment layout (per block; L2/L3-cached) ----
    #pragma unroll
    for (int p = 0; p < 5; p++) {
        const float* wp = (p == 0) ? wA : (p == 1) ? wB : (p == 2) ? wC : (p == 3) ? wD : wE;
        for (int rem = tid; rem < 4096; rem += 256) {   // rem = k*16 + w ; global idx == rem
            int k = rem >> 4;
            int w = rem & 15;
            int c = k >> 5, kk = k & 31;
            int lane = ((kk >> 3) << 4) | w;
            int j = kk & 7;
            wlds[(((p * 8 + c) * 64 + lane) << 3) | j] = f2bfu(wp[rem]);
        }
    }

    // ---- Phase 1: stage x tile (coalesced float4) ----
    {
        const long long rowbase = (long long)blockIdx.x * 64;
        const float* xg = x + rowbase * 64;
        #pragma unroll
        for (int q = 0; q < 4; q++) {
            int f = q * 1024 + tid * 4;
            int row = f >> 6, col = f & 63;
            float4v v = {0.f, 0.f, 0.f, 0.f};
            if (rowbase + row < nrows) v = *(const float4v*)(xg + f);
            *(float4v*)&xlds[row * 68 + col] = v;
        }
    }
    __syncthreads();

    const int wave = tid >> 6;
    const int l = tid & 63;
    const long long z0 = (long long)blockIdx.x * 64 + wave * 16;
    if (z0 >= nrows) return;

    const int r  = l & 15;        // my A-row (z-local) for building, my w-col for output
    const int g  = l >> 4;        // quad
    const int v0 = (g & 1) * 8;   // my v-range base (fixed for all chunks)
    const int uo = g >> 1;        // u = c*2 + uo
    const float* xr = &xlds[(wave * 16 + r) * 68];

    // v-side x cached in registers (constant across chunks)
    float av[8], bx[8], byv[8], bzv[8];
    #pragma unroll
    for (int j = 0; j < 8; j++) {
        av[j]  = xr[v0 + j];                 // x0[v]
        bx[j]  = xr[16 + (v0 + j) * 3 + 0];  // x1[v].x
        byv[j] = xr[16 + (v0 + j) * 3 + 1];
        bzv[j] = xr[16 + (v0 + j) * 3 + 2];
    }

    float4v acc[13];
    #pragma unroll
    for (int m = 0; m < 13; m++) acc[m] = (float4v){0.f, 0.f, 0.f, 0.f};

    // m-slot -> path: 0:w0  1:w2  2-4:w1  5-7:w3  8-12:w4
    constexpr int pm[13] = {0, 1, 2, 2, 2, 3, 3, 3, 4, 4, 4, 4, 4};

    #pragma unroll
    for (int c = 0; c < 8; c++) {
        const int u = c * 2 + uo;
        const float u0 = xr[u];
        const float ux = xr[16 + u * 3 + 0];
        const float uy = xr[16 + u * 3 + 1];
        const float uz = xr[16 + u * 3 + 2];

        int4v fri[13];
        #pragma unroll
        for (int t = 0; t < 4; t++) {
            float bva[13], bvb[13];
            auto build = [&](int j, float* bv) {
                const float A0 = av[j], X = bx[j], Y = byv[j], Z = bzv[j];
                const float p00 = ux * X, p01 = ux * Y, p02 = ux * Z;
                const float p10 = uy * X, p11 = uy * Y, p12 = uy * Z;
                const float p20 = uz * X, p21 = uz * Y, p22 = uz * Z;
                bv[0]  = u0 * A0;                     // 0e x 0e
                bv[1]  = p00 + p11 + p22;             // dot (scale 1/sqrt3 in epilogue)
                bv[2]  = u0 * X;                      // 0e x 1o
                bv[3]  = u0 * Y;
                bv[4]  = u0 * Z;
                bv[5]  = p12 - p21;                   // cross (scale s2 in epilogue)
                bv[6]  = p20 - p02;
                bv[7]  = p01 - p10;
                bv[8]  = p01 + p10;                   // 2e: xy
                bv[9]  = p12 + p21;                   //     yz
                bv[10] = 2.0f * p22 - p00 - p11;      //     3z^2-r^2 (scale 1/sqrt6)
                bv[11] = p02 + p20;                   //     xz
                bv[12] = p00 - p11;                   //     x^2-y^2 (scale s2)
            };
            build(2 * t, bva);
            build(2 * t + 1, bvb);
            #pragma unroll
            for (int m = 0; m < 13; m++) fri[m][t] = (int)pack_bf2(bva[m], bvb[m]);
        }

        short8 wf[5];
        #pragma unroll
        for (int p = 0; p < 5; p++)
            wf[p] = *(const short8*)&wlds[(((p * 8 + c) * 64 + l) << 3)];

        #pragma unroll
        for (int m = 0; m < 13; m++) {
            short8 frm = __builtin_bit_cast(short8, fri[m]);
            acc[m] = __builtin_amdgcn_mfma_f32_16x16x32_bf16(frm, wf[pm[m]], acc[m], 0, 0, 0);
        }
    }

    // ---- Epilogue: scale + store. lane: w = l&15, rows z0 + (l>>4)*4 + reg ----
    const int w = r;
    float* outp = out + (z0 + g * 4) * 192;
    #pragma unroll
    for (int reg = 0; reg < 4; reg++) {
        float* rowp = outp + reg * 192;
        rowp[w] = S_A * acc[0][reg] + S_B * acc[1][reg];      // 0e (two paths summed)
        rowp[16 + w * 3 + 0]  = S_C * acc[2][reg];            // 1o
        rowp[16 + w * 3 + 1]  = S_C * acc[3][reg];
        rowp[16 + w * 3 + 2]  = S_C * acc[4][reg];
        rowp[64 + w * 3 + 0]  = S_A * acc[5][reg];            // 1e
        rowp[64 + w * 3 + 1]  = S_A * acc[6][reg];
        rowp[64 + w * 3 + 2]  = S_A * acc[7][reg];
        rowp[112 + w * 5 + 0] = S_A * acc[8][reg];            // 2e
        rowp[112 + w * 5 + 1] = S_A * acc[9][reg];
        rowp[112 + w * 5 + 2] = S_B * acc[10][reg];
        rowp[112 + w * 5 + 3] = S_A * acc[11][reg];
        rowp[112 + w * 5 + 4] = S_A * acc[12][reg];
    }
}

extern "C" void kernel_launch(void* const* d_in, const int* in_sizes, int n_in,
                              void* d_out, int out_size, void* d_ws, size_t ws_size,
                              hipStream_t stream) {
    const float* x  = (const float*)d_in[0];
    const float* w0 = (const float*)d_in[1];
    const float* w1 = (const float*)d_in[2];
    const float* w2 = (const float*)d_in[3];
    const float* w3 = (const float*)d_in[4];
    const float* w4 = (const float*)d_in[5];
    float* out = (float*)d_out;
    (void)d_ws; (void)ws_size; (void)n_in;

    const int nrows = in_sizes[0] / 64;          // 100000
    const int nblocks = (nrows + 63) / 64;       // 1563
    // path order: {w0, w2, w1, w3, w4}
    tsq_kernel<<<dim3(nblocks), dim3(256), 0, stream>>>(x, w0, w2, w1, w3, w4, out, nrows);
}